// Round 21
// baseline (48.568 us; speedup 1.0000x reference)
//
#include <hip/hip_runtime.h>
#include <math.h>
#include <stdint.h>

#define T_TOK 8192
#define DDIM  4096
#define NEXP  64
#define TOPK  8
#define BK    32        // k per 2-phase step
#define RS    2048.0f

typedef __attribute__((ext_vector_type(8))) _Float16 half8;
typedef __attribute__((ext_vector_type(4))) float f32x4;
typedef __attribute__((address_space(3))) uint32_t lds_u32;
typedef const __attribute__((address_space(1))) uint32_t glb_u32;

// ---- K1a: MT=256 tile, 8 waves each owning 32 tok x ALL 64 experts. ----
// S=16 K-split -> STEPS=8: half the barrier stalls of R19 at 2x per-step
// work; LDS 80 KB -> still 2 blocks/CU; grid 512 -> 2/CU.
// A: global_load_lds, src slot-swizzle c^(row&7), double-buffered.
// B: global_load_lds per-lane fragment-gather from gw (R19), f16 split in-loop
//    (A-split hoisted per step; B-split per-nf to cap VGPR pressure).
template<int STEPS, int S>
__global__ __launch_bounds__(512, 4) void gemm_part256(
    const float* __restrict__ x, const float* __restrict__ gw,
    float* __restrict__ part)
{
    __shared__ float A[2][256 * BK];             // 2 x 32 KB
    __shared__ float Bf[2][2048];                // 2 x  8 KB: [n*2+h][lane][4]

    const int tid  = threadIdx.x;
    const int lane = tid & 63;
    const int wv   = tid >> 6;                   // wave: M-octant (32 rows)
    const int slc  = blockIdx.x % S;             // K-slice
    const int mt   = blockIdx.x / S;             // token tile (0..31)
    const int m0   = mt * 256;
    const int kt0  = slc * STEPS;                // 32-k units
    const int am   = lane & 15;
    const int ag   = lane >> 4;

    // B staging role: n-frag = wv&3, half = wv>>2 (8 waves cover 4n x 2h)
    const int bn = wv & 3;
    const int bh = wv >> 2;
    const float* gB = gw + (size_t)(bn * 16 + am) * DDIM
                    + (size_t)kt0 * BK + ag * 8 + bh * 4;

#define STAGE(buf_, t_) do {                                                   \
        const size_t koff = (size_t)(kt0 + (t_)) * BK;                         \
        _Pragma("unroll")                                                      \
        for (int r_ = 0; r_ < 4; r_++) {                                       \
            int idx_ = r_ * 512 + tid;                                         \
            int row_ = idx_ >> 3;                                              \
            int c_   = idx_ & 7;                                               \
            int cs_  = c_ ^ (row_ & 7);                                        \
            __builtin_amdgcn_global_load_lds(                                  \
                (glb_u32*)(x + (size_t)(m0 + row_) * DDIM + koff + cs_ * 4),   \
                (lds_u32*)(&A[buf_][idx_ * 4]), 16, 0, 0);                     \
        }                                                                      \
        __builtin_amdgcn_global_load_lds(                                      \
            (glb_u32*)(gB + (size_t)(t_) * BK),                                \
            (lds_u32*)(&Bf[buf_][((bn * 2 + bh) * 64 + lane) * 4]), 16, 0, 0); \
    } while (0)

    f32x4 aH[2][4], aM[2][4];                    // [m-frag][n-frag]
    #pragma unroll
    for (int f = 0; f < 2; f++)
        #pragma unroll
        for (int n = 0; n < 4; n++) {
            aH[f][n] = (f32x4){0.f, 0.f, 0.f, 0.f};
            aM[f][n] = (f32x4){0.f, 0.f, 0.f, 0.f};
        }

    STAGE(0, 0);
    __syncthreads();                             // buf0 ready

    for (int t = 0; t < STEPS; t++) {
        const int buf = t & 1;
        if (t + 1 < STEPS) STAGE(buf ^ 1, t + 1);    // async FIFO prefetch

        // ---- A frags: read + split once per step (hoisted) ----
        half8 a0[2], a1[2];
        #pragma unroll
        for (int f = 0; f < 2; f++) {
            const int row = wv * 32 + f * 16 + am;
            const int sw  = am & 7;              // row&7 == am&7
            float4 alo = *reinterpret_cast<const float4*>(
                &A[buf][row * BK + ((ag * 2 + 0) ^ sw) * 4]);
            float4 ahi = *reinterpret_cast<const float4*>(
                &A[buf][row * BK + ((ag * 2 + 1) ^ sw) * 4]);
            const float vv[8] = {alo.x, alo.y, alo.z, alo.w,
                                 ahi.x, ahi.y, ahi.z, ahi.w};
            #pragma unroll
            for (int j = 0; j < 8; j++) {
                float v = vv[j];
                _Float16 h = (_Float16)v;
                a0[f][j] = h;
                a1[f][j] = (_Float16)((v - (float)h) * RS);
            }
        }

        // ---- per n-frag: B split (8 VGPR live) + 6 MFMAs ----
        #pragma unroll
        for (int nf = 0; nf < 4; nf++) {
            float4 u0 = *reinterpret_cast<const float4*>(
                &Bf[buf][((nf * 2 + 0) * 64 + lane) * 4]);
            float4 u1 = *reinterpret_cast<const float4*>(
                &Bf[buf][((nf * 2 + 1) * 64 + lane) * 4]);
            const float bv[8] = {u0.x, u0.y, u0.z, u0.w, u1.x, u1.y, u1.z, u1.w};
            half8 B0, B1;
            #pragma unroll
            for (int j = 0; j < 8; j++) {
                float v = bv[j];
                _Float16 h = (_Float16)v;
                B0[j] = h;
                B1[j] = (_Float16)((v - (float)h) * RS);
            }
            #pragma unroll
            for (int f = 0; f < 2; f++) {
                aH[f][nf] = __builtin_amdgcn_mfma_f32_16x16x32_f16(a0[f], B0, aH[f][nf], 0, 0, 0);
                aM[f][nf] = __builtin_amdgcn_mfma_f32_16x16x32_f16(a0[f], B1, aM[f][nf], 0, 0, 0);
                aM[f][nf] = __builtin_amdgcn_mfma_f32_16x16x32_f16(a1[f], B0, aM[f][nf], 0, 0, 0);
            }
        }
        __syncthreads();
    }
#undef STAGE

    // ---- write partials: part[slc][token][expert] ----
    // C/D layout (m89): col = lane&15 (expert), row = (lane>>4)*4 + r (token)
    const float i1 = 1.0f / RS;
    float* po = part + (size_t)slc * T_TOK * NEXP + (size_t)m0 * NEXP;
    #pragma unroll
    for (int f = 0; f < 2; f++)
        #pragma unroll
        for (int nf = 0; nf < 4; nf++)
            #pragma unroll
            for (int r = 0; r < 4; r++)
                po[(size_t)(wv * 32 + f * 16 + ag * 4 + r) * NEXP
                   + nf * 16 + am]
                    = aH[f][nf][r] + aM[f][nf][r] * i1;
}

// ---- K1b (fallback, R19 exact): MT=128, 2 N-halves ----
template<int STEPS, int S>
__global__ __launch_bounds__(512) void gemm_part128(
    const float* __restrict__ x, const float* __restrict__ gw,
    float* __restrict__ part)
{
    __shared__ float A[2][128 * BK];
    __shared__ float Bf[2][2048];

    const int tid  = threadIdx.x;
    const int lane = tid & 63;
    const int wv   = tid >> 6;
    const int wm   = wv & 3;
    const int wn   = wv >> 2;
    const int slc  = blockIdx.x % S;
    const int mt   = blockIdx.x / S;
    const int m0   = mt * 128;
    const int kt0  = slc * STEPS;
    const int am   = lane & 15;
    const int ag   = lane >> 4;

    const int s_row0 = tid >> 3;
    const int s_c    = tid & 7;

    const int bn = wv & 3;
    const int bh = wv >> 2;
    const float* gB = gw + (size_t)(bn * 16 + am) * DDIM
                    + (size_t)kt0 * BK + ag * 8 + bh * 4;

#define STAGE(buf_, t_) do {                                                   \
        const size_t koff = (size_t)(kt0 + (t_)) * BK;                         \
        int c0 = s_c ^ (s_row0 & 7);                                           \
        __builtin_amdgcn_global_load_lds(                                      \
            (glb_u32*)(x + (size_t)(m0 + s_row0) * DDIM + koff + c0 * 4),      \
            (lds_u32*)(&A[buf_][tid * 4]), 16, 0, 0);                          \
        int r1 = s_row0 + 64;                                                  \
        int c1 = s_c ^ (r1 & 7);                                               \
        __builtin_amdgcn_global_load_lds(                                      \
            (glb_u32*)(x + (size_t)(m0 + r1) * DDIM + koff + c1 * 4),          \
            (lds_u32*)(&A[buf_][2048 + tid * 4]), 16, 0, 0);                   \
        __builtin_amdgcn_global_load_lds(                                      \
            (glb_u32*)(gB + (size_t)(t_) * BK),                                \
            (lds_u32*)(&Bf[buf_][((bn * 2 + bh) * 64 + lane) * 4]), 16, 0, 0); \
    } while (0)

    f32x4 aH[2][2], aM[2][2];
    #pragma unroll
    for (int f = 0; f < 2; f++)
        #pragma unroll
        for (int n = 0; n < 2; n++) {
            aH[f][n] = (f32x4){0.f, 0.f, 0.f, 0.f};
            aM[f][n] = (f32x4){0.f, 0.f, 0.f, 0.f};
        }

    STAGE(0, 0);
    __syncthreads();

    #pragma unroll 2
    for (int t = 0; t < STEPS; t++) {
        const int buf = t & 1;
        if (t + 1 < STEPS) STAGE(buf ^ 1, t + 1);

        half8 B0[2], B1[2];
        #pragma unroll
        for (int nf = 0; nf < 2; nf++) {
            const int n = wn * 2 + nf;
            float4 u0 = *reinterpret_cast<const float4*>(
                &Bf[buf][((n * 2 + 0) * 64 + lane) * 4]);
            float4 u1 = *reinterpret_cast<const float4*>(
                &Bf[buf][((n * 2 + 1) * 64 + lane) * 4]);
            const float bv[8] = {u0.x, u0.y, u0.z, u0.w, u1.x, u1.y, u1.z, u1.w};
            #pragma unroll
            for (int j = 0; j < 8; j++) {
                float v = bv[j];
                _Float16 h = (_Float16)v;
                B0[nf][j] = h;
                B1[nf][j] = (_Float16)((v - (float)h) * RS);
            }
        }
        #pragma unroll
        for (int f = 0; f < 2; f++) {
            const int row = wm * 32 + f * 16 + am;
            const int sw  = am & 7;
            float4 alo = *reinterpret_cast<const float4*>(
                &A[buf][row * BK + ((ag * 2 + 0) ^ sw) * 4]);
            float4 ahi = *reinterpret_cast<const float4*>(
                &A[buf][row * BK + ((ag * 2 + 1) ^ sw) * 4]);
            const float vv[8] = {alo.x, alo.y, alo.z, alo.w,
                                 ahi.x, ahi.y, ahi.z, ahi.w};
            half8 a0, a1;
            #pragma unroll
            for (int j = 0; j < 8; j++) {
                float v = vv[j];
                _Float16 h = (_Float16)v;
                a0[j] = h;
                a1[j] = (_Float16)((v - (float)h) * RS);
            }
            #pragma unroll
            for (int nf = 0; nf < 2; nf++) {
                aH[f][nf] = __builtin_amdgcn_mfma_f32_16x16x32_f16(a0, B0[nf], aH[f][nf], 0, 0, 0);
                aM[f][nf] = __builtin_amdgcn_mfma_f32_16x16x32_f16(a0, B1[nf], aM[f][nf], 0, 0, 0);
                aM[f][nf] = __builtin_amdgcn_mfma_f32_16x16x32_f16(a1, B0[nf], aM[f][nf], 0, 0, 0);
            }
        }
        __syncthreads();
    }
#undef STAGE

    const float i1 = 1.0f / RS;
    float* po = part + (size_t)slc * T_TOK * NEXP + (size_t)m0 * NEXP;
    #pragma unroll
    for (int f = 0; f < 2; f++)
        #pragma unroll
        for (int nf = 0; nf < 2; nf++)
            #pragma unroll
            for (int r = 0; r < 4; r++)
                po[(size_t)(wm * 32 + f * 16 + ag * 4 + r) * NEXP
                   + (wn * 2 + nf) * 16 + am]
                    = aH[f][nf][r] + aM[f][nf][r] * i1;
}

// ---- K2: reduce partials, sigmoid, +bias, top-8, normalize ----
__global__ __launch_bounds__(256) void reduce_topk(
    const float* __restrict__ part, const float* __restrict__ bias,
    float* __restrict__ out, int S)
{
    const int wave = threadIdx.x >> 6;
    const int lane = threadIdx.x & 63;
    const int j    = blockIdx.x;                 // 0..2047
    const int g    = j & 7;
    const int q    = j >> 3;
    const int token = g * 128 + (q & 31) * 4 + (q >> 5) * 1024 + wave;
    if (token >= T_TOK) return;

    float logit = 0.f;
    for (int s = 0; s < S; s++)
        logit += part[(size_t)s * T_TOK * NEXP + (size_t)token * NEXP + lane];

    float score  = 1.f / (1.f + expf(-logit));
    float biased = score + bias[lane];

    float my_sc = 0.f;
    int   my_idx = 0;
    float ssum  = 0.f;

    #pragma unroll
    for (int jj = 0; jj < TOPK; jj++) {
        float v = biased;
        int   i = lane;
        #pragma unroll
        for (int off = 32; off >= 1; off >>= 1) {
            float ov = __shfl_xor(v, off);
            int   oi = __shfl_xor(i, off);
            if (ov > v || (ov == v && oi < i)) { v = ov; i = oi; }
        }
        float s_sel = __shfl(score, i);
        ssum += s_sel;
        if (lane == jj) { my_idx = i; my_sc = s_sel; }
        if (lane == i) biased = -INFINITY;
    }

    if (lane < TOPK) {
        out[(size_t)token * TOPK + lane] = (float)my_idx;                 // indices as f32
        out[(size_t)T_TOK * TOPK + (size_t)token * TOPK + lane]
            = my_sc / (ssum + 1e-20f);                                    // weights
    }
}

extern "C" void kernel_launch(void* const* d_in, const int* in_sizes, int n_in,
                              void* d_out, int out_size, void* d_ws, size_t ws_size,
                              hipStream_t stream) {
    (void)in_sizes; (void)n_in; (void)out_size;
    const float* x    = (const float*)d_in[0];
    const float* gw   = (const float*)d_in[1];
    const float* bias = (const float*)d_in[2];
    float* out  = (float*)d_out;
    float* part = (float*)d_ws;                  // S x [T][E] f32

    const size_t per_slice = (size_t)T_TOK * NEXP * sizeof(float);       // 2 MiB
    int S = 1;
    for (int cand : {16, 8, 4, 2}) {
        if ((size_t)cand * per_slice <= ws_size) { S = cand; break; }
    }

    dim3 b1(512);
    switch (S) {
        case 16: gemm_part256< 8, 16><<<dim3(32 * 16), b1, 0, stream>>>(x, gw, part); break;
        case  8: gemm_part128<16,  8><<<dim3(64 *  8), b1, 0, stream>>>(x, gw, part); break;
        case  4: gemm_part128<32,  4><<<dim3(64 *  4), b1, 0, stream>>>(x, gw, part); break;
        case  2: gemm_part128<64,  2><<<dim3(64 *  2), b1, 0, stream>>>(x, gw, part); break;
        default: gemm_part128<128, 1><<<dim3(64), b1, 0, stream>>>(x, gw, part); break;
    }

    reduce_topk<<<dim3(T_TOK / 4), 256, 0, stream>>>(part, bias, out, S);
}

// Round 22
// 47.020 us; speedup vs baseline: 1.0329x; 1.0329x over previous
//
#include <hip/hip_runtime.h>
#include <math.h>
#include <stdint.h>

#define T_TOK 8192
#define DDIM  4096
#define NEXP  64
#define TOPK  8
#define MT    128       // tokens per block
#define BK    32        // k per 2-phase step
#define RS    2048.0f

typedef __attribute__((ext_vector_type(8))) _Float16 half8;
typedef __attribute__((ext_vector_type(4))) float f32x4;
typedef __attribute__((address_space(3))) uint32_t lds_u32;
typedef const __attribute__((address_space(1))) uint32_t glb_u32;

// ---- K1: 2-phase LDS-staged MFMA partials; B gather-staged from gw ----
// (R19 structure, best measured: 45.96 us total.)
// 512 thr = 8 waves = 4 M-quarters x 2 N-halves; tile 128 tok x 64 exp.
// slc = bid % S (XCD-aligned K-slices); mt = bid / S.
// A: global_load_lds, src slot-swizzle c^(row&7).
// B: global_load_lds with PER-LANE fragment-gather source (m104) ->
//    LDS [n][half][lane][16B]; f16 split in-loop.  No pack kernel.
// R22 delta: partials stored INTERLEAVED part[token][slc][expert] so K2
// reads each token as one contiguous 2 KB chunk (was 8 x 2MiB-strided).
template<int STEPS, int S>
__global__ __launch_bounds__(512) void gemm_part(
    const float* __restrict__ x, const float* __restrict__ gw,
    float* __restrict__ part)
{
    __shared__ float A[2][MT * BK];              // 2 x 16 KB
    __shared__ float Bf[2][2048];                // 2 x  8 KB: [n*2+h][lane][4]

    const int tid  = threadIdx.x;
    const int lane = tid & 63;
    const int wv   = tid >> 6;
    const int wm   = wv & 3;                     // M-quarter (32 rows)
    const int wn   = wv >> 2;                    // N-half (32 experts)
    const int slc  = blockIdx.x % S;             // K-slice == XCD (bid%8)
    const int mt   = blockIdx.x / S;             // token tile
    const int m0   = mt * MT;
    const int kt0  = slc * STEPS;                // 32-k units
    const int am   = lane & 15;
    const int ag   = lane >> 4;

    const int s_row0 = tid >> 3;                 // A staging row (0..63)
    const int s_c    = tid & 7;                  // A float4 col

    // B staging role for this thread's wave: n-frag = wv&3, half = wv>>2
    const int bn = wv & 3;
    const int bh = wv >> 2;
    const float* gB = gw + (size_t)(bn * 16 + am) * DDIM
                    + (size_t)kt0 * BK + ag * 8 + bh * 4;

#define STAGE(buf_, t_) do {                                                   \
        const size_t koff = (size_t)(kt0 + (t_)) * BK;                         \
        int c0 = s_c ^ (s_row0 & 7);                                           \
        __builtin_amdgcn_global_load_lds(                                      \
            (glb_u32*)(x + (size_t)(m0 + s_row0) * DDIM + koff + c0 * 4),      \
            (lds_u32*)(&A[buf_][tid * 4]), 16, 0, 0);                          \
        int r1 = s_row0 + 64;                                                  \
        int c1 = s_c ^ (r1 & 7);                                               \
        __builtin_amdgcn_global_load_lds(                                      \
            (glb_u32*)(x + (size_t)(m0 + r1) * DDIM + koff + c1 * 4),          \
            (lds_u32*)(&A[buf_][2048 + tid * 4]), 16, 0, 0);                   \
        __builtin_amdgcn_global_load_lds(                                      \
            (glb_u32*)(gB + (size_t)(t_) * BK),                                \
            (lds_u32*)(&Bf[buf_][((bn * 2 + bh) * 64 + lane) * 4]), 16, 0, 0); \
    } while (0)

    f32x4 aH[2][2], aM[2][2];
    #pragma unroll
    for (int f = 0; f < 2; f++)
        #pragma unroll
        for (int n = 0; n < 2; n++) {
            aH[f][n] = (f32x4){0.f, 0.f, 0.f, 0.f};
            aM[f][n] = (f32x4){0.f, 0.f, 0.f, 0.f};
        }

    STAGE(0, 0);
    __syncthreads();                             // buf0 ready

    #pragma unroll 2
    for (int t = 0; t < STEPS; t++) {
        const int buf = t & 1;
        if (t + 1 < STEPS) STAGE(buf ^ 1, t + 1);    // async FIFO prefetch

        // ---- B frags: two b128 LDS reads + in-loop f16 split ----
        half8 B0[2], B1[2];
        #pragma unroll
        for (int nf = 0; nf < 2; nf++) {
            const int n = wn * 2 + nf;
            float4 u0 = *reinterpret_cast<const float4*>(
                &Bf[buf][((n * 2 + 0) * 64 + lane) * 4]);
            float4 u1 = *reinterpret_cast<const float4*>(
                &Bf[buf][((n * 2 + 1) * 64 + lane) * 4]);
            const float bv[8] = {u0.x, u0.y, u0.z, u0.w, u1.x, u1.y, u1.z, u1.w};
            #pragma unroll
            for (int j = 0; j < 8; j++) {
                float v = bv[j];
                _Float16 h = (_Float16)v;
                B0[nf][j] = h;
                B1[nf][j] = (_Float16)((v - (float)h) * RS);
            }
        }

        #pragma unroll
        for (int f = 0; f < 2; f++) {
            const int row = wm * 32 + f * 16 + am;
            const int sw  = am & 7;              // row&7 == am&7
            float4 alo = *reinterpret_cast<const float4*>(
                &A[buf][row * BK + ((ag * 2 + 0) ^ sw) * 4]);
            float4 ahi = *reinterpret_cast<const float4*>(
                &A[buf][row * BK + ((ag * 2 + 1) ^ sw) * 4]);
            const float vv[8] = {alo.x, alo.y, alo.z, alo.w,
                                 ahi.x, ahi.y, ahi.z, ahi.w};
            half8 a0, a1;
            #pragma unroll
            for (int j = 0; j < 8; j++) {
                float v = vv[j];
                _Float16 h = (_Float16)v;
                a0[j] = h;
                a1[j] = (_Float16)((v - (float)h) * RS);
            }
            #pragma unroll
            for (int nf = 0; nf < 2; nf++) {
                aH[f][nf] = __builtin_amdgcn_mfma_f32_16x16x32_f16(a0, B0[nf], aH[f][nf], 0, 0, 0);
                aM[f][nf] = __builtin_amdgcn_mfma_f32_16x16x32_f16(a0, B1[nf], aM[f][nf], 0, 0, 0);
                aM[f][nf] = __builtin_amdgcn_mfma_f32_16x16x32_f16(a1, B0[nf], aM[f][nf], 0, 0, 0);
            }
        }
        __syncthreads();
    }
#undef STAGE

    // ---- write partials INTERLEAVED: part[token][slc][expert] ----
    // C/D layout (m89): col = lane&15 (expert), row = (lane>>4)*4 + r (token)
    const float i1 = 1.0f / RS;
    float* po = part + (size_t)m0 * (S * NEXP) + (size_t)slc * NEXP;
    #pragma unroll
    for (int f = 0; f < 2; f++)
        #pragma unroll
        for (int nf = 0; nf < 2; nf++)
            #pragma unroll
            for (int r = 0; r < 4; r++)
                po[(size_t)(wm * 32 + f * 16 + ag * 4 + r) * (S * NEXP)
                   + (wn * 2 + nf) * 16 + am]
                    = aH[f][nf][r] + aM[f][nf][r] * i1;
}

// ---- K2: reduce interleaved partials, sigmoid, +bias, top-8, normalize ----
// part[token][slc][expert]: each token = one contiguous S*64-float chunk ->
// the wave's 8 reduce reads are 8 coalesced 256B segments in a single 2KB
// region (was 8 x 2MiB-strided).
__global__ __launch_bounds__(256) void reduce_topk(
    const float* __restrict__ part, const float* __restrict__ bias,
    float* __restrict__ out, int S)
{
    const int wave  = threadIdx.x >> 6;
    const int lane  = threadIdx.x & 63;
    const int token = blockIdx.x * 4 + wave;
    if (token >= T_TOK) return;

    const float* base = part + (size_t)token * (S * NEXP);
    float logit = 0.f;
    for (int s = 0; s < S; s++)
        logit += base[s * NEXP + lane];

    float score  = 1.f / (1.f + expf(-logit));
    float biased = score + bias[lane];

    float my_sc = 0.f;
    int   my_idx = 0;
    float ssum  = 0.f;

    #pragma unroll
    for (int jj = 0; jj < TOPK; jj++) {
        float v = biased;
        int   i = lane;
        #pragma unroll
        for (int off = 32; off >= 1; off >>= 1) {
            float ov = __shfl_xor(v, off);
            int   oi = __shfl_xor(i, off);
            if (ov > v || (ov == v && oi < i)) { v = ov; i = oi; }
        }
        float s_sel = __shfl(score, i);
        ssum += s_sel;
        if (lane == jj) { my_idx = i; my_sc = s_sel; }
        if (lane == i) biased = -INFINITY;
    }

    if (lane < TOPK) {
        out[(size_t)token * TOPK + lane] = (float)my_idx;                 // indices as f32
        out[(size_t)T_TOK * TOPK + (size_t)token * TOPK + lane]
            = my_sc / (ssum + 1e-20f);                                    // weights
    }
}

extern "C" void kernel_launch(void* const* d_in, const int* in_sizes, int n_in,
                              void* d_out, int out_size, void* d_ws, size_t ws_size,
                              hipStream_t stream) {
    (void)in_sizes; (void)n_in; (void)out_size;
    const float* x    = (const float*)d_in[0];
    const float* gw   = (const float*)d_in[1];
    const float* bias = (const float*)d_in[2];
    float* out  = (float*)d_out;
    float* part = (float*)d_ws;                  // [T][S][E] f32

    const size_t per_slice = (size_t)T_TOK * NEXP * sizeof(float);       // 2 MiB
    int S = 1;
    for (int cand : {8, 4, 2}) {
        if ((size_t)cand * per_slice <= ws_size) { S = cand; break; }
    }

    dim3 b1(512);
    switch (S) {
        case 8: gemm_part<16, 8><<<dim3(64 * 8), b1, 0, stream>>>(x, gw, part); break;
        case 4: gemm_part<32, 4><<<dim3(64 * 4), b1, 0, stream>>>(x, gw, part); break;
        case 2: gemm_part<64, 2><<<dim3(64 * 2), b1, 0, stream>>>(x, gw, part); break;
        default: gemm_part<128, 1><<<dim3(64), b1, 0, stream>>>(x, gw, part); break;
    }

    reduce_topk<<<dim3(T_TOK / 4), 256, 0, stream>>>(part, bias, out, S);
}

// Round 23
// 45.840 us; speedup vs baseline: 1.0595x; 1.0257x over previous
//
#include <hip/hip_runtime.h>
#include <math.h>
#include <stdint.h>

#define T_TOK 8192
#define DDIM  4096
#define NEXP  64
#define TOPK  8
#define MT    128       // tokens per block
#define BK    32        // k per 2-phase step
#define RS    2048.0f

typedef __attribute__((ext_vector_type(8))) _Float16 half8;
typedef __attribute__((ext_vector_type(4))) float f32x4;
typedef __attribute__((address_space(3))) uint32_t lds_u32;
typedef const __attribute__((address_space(1))) uint32_t glb_u32;

// ---- K1: 2-phase LDS-staged MFMA partials; B gather-staged from gw ----
// (R19 structure — best measured: 45.96 us total, absmax 0.)
// 512 thr = 8 waves = 4 M-quarters x 2 N-halves; tile 128 tok x 64 exp.
// slc = bid % S (XCD-aligned K-slices, R16); mt = bid / S.
// A: global_load_lds, src slot-swizzle c^(row&7) (R11).
// B: global_load_lds with PER-LANE fragment-gather source (m104: src is
//    per-lane, dest is base+lane*16) -> LDS [n][half][lane][16B]; f16 split
//    done in-loop.  No pack kernel, no wpk round-trip; B loads stay in the
//    async FIFO (R17's register-direct B was the critical-path mistake).
template<int STEPS, int S>
__global__ __launch_bounds__(512) void gemm_part(
    const float* __restrict__ x, const float* __restrict__ gw,
    float* __restrict__ part)
{
    __shared__ float A[2][MT * BK];              // 2 x 16 KB
    __shared__ float Bf[2][2048];                // 2 x  8 KB: [n*2+h][lane][4]

    const int tid  = threadIdx.x;
    const int lane = tid & 63;
    const int wv   = tid >> 6;
    const int wm   = wv & 3;                     // M-quarter (32 rows)
    const int wn   = wv >> 2;                    // N-half (32 experts)
    const int slc  = blockIdx.x % S;             // K-slice == XCD (bid%8)
    const int mt   = blockIdx.x / S;             // token tile
    const int m0   = mt * MT;
    const int kt0  = slc * STEPS;                // 32-k units
    const int am   = lane & 15;
    const int ag   = lane >> 4;

    const int s_row0 = tid >> 3;                 // A staging row (0..63)
    const int s_c    = tid & 7;                  // A float4 col

    // B staging role for this thread's wave: n-frag = wv&3, half = wv>>2
    const int bn = wv & 3;
    const int bh = wv >> 2;
    const float* gB = gw + (size_t)(bn * 16 + am) * DDIM   // expert row
                    + (size_t)kt0 * BK + ag * 8 + bh * 4;  // k offset

#define STAGE(buf_, t_) do {                                                   \
        const size_t koff = (size_t)(kt0 + (t_)) * BK;                         \
        int c0 = s_c ^ (s_row0 & 7);                                           \
        __builtin_amdgcn_global_load_lds(                                      \
            (glb_u32*)(x + (size_t)(m0 + s_row0) * DDIM + koff + c0 * 4),      \
            (lds_u32*)(&A[buf_][tid * 4]), 16, 0, 0);                          \
        int r1 = s_row0 + 64;                                                  \
        int c1 = s_c ^ (r1 & 7);                                               \
        __builtin_amdgcn_global_load_lds(                                      \
            (glb_u32*)(x + (size_t)(m0 + r1) * DDIM + koff + c1 * 4),          \
            (lds_u32*)(&A[buf_][2048 + tid * 4]), 16, 0, 0);                   \
        __builtin_amdgcn_global_load_lds(                                      \
            (glb_u32*)(gB + (size_t)(t_) * BK),                                \
            (lds_u32*)(&Bf[buf_][((bn * 2 + bh) * 64 + lane) * 4]), 16, 0, 0); \
    } while (0)

    f32x4 aH[2][2], aM[2][2];
    #pragma unroll
    for (int f = 0; f < 2; f++)
        #pragma unroll
        for (int n = 0; n < 2; n++) {
            aH[f][n] = (f32x4){0.f, 0.f, 0.f, 0.f};
            aM[f][n] = (f32x4){0.f, 0.f, 0.f, 0.f};
        }

    STAGE(0, 0);
    __syncthreads();                             // buf0 ready

    #pragma unroll 2
    for (int t = 0; t < STEPS; t++) {
        const int buf = t & 1;
        if (t + 1 < STEPS) STAGE(buf ^ 1, t + 1);    // async FIFO prefetch

        // ---- B frags: two b128 LDS reads + in-loop f16 split ----
        half8 B0[2], B1[2];
        #pragma unroll
        for (int nf = 0; nf < 2; nf++) {
            const int n = wn * 2 + nf;
            float4 u0 = *reinterpret_cast<const float4*>(
                &Bf[buf][((n * 2 + 0) * 64 + lane) * 4]);
            float4 u1 = *reinterpret_cast<const float4*>(
                &Bf[buf][((n * 2 + 1) * 64 + lane) * 4]);
            const float bv[8] = {u0.x, u0.y, u0.z, u0.w, u1.x, u1.y, u1.z, u1.w};
            #pragma unroll
            for (int j = 0; j < 8; j++) {
                float v = bv[j];
                _Float16 h = (_Float16)v;
                B0[nf][j] = h;
                B1[nf][j] = (_Float16)((v - (float)h) * RS);
            }
        }

        #pragma unroll
        for (int f = 0; f < 2; f++) {
            const int row = wm * 32 + f * 16 + am;
            const int sw  = am & 7;              // row&7 == am&7
            float4 alo = *reinterpret_cast<const float4*>(
                &A[buf][row * BK + ((ag * 2 + 0) ^ sw) * 4]);
            float4 ahi = *reinterpret_cast<const float4*>(
                &A[buf][row * BK + ((ag * 2 + 1) ^ sw) * 4]);
            const float vv[8] = {alo.x, alo.y, alo.z, alo.w,
                                 ahi.x, ahi.y, ahi.z, ahi.w};
            half8 a0, a1;
            #pragma unroll
            for (int j = 0; j < 8; j++) {
                float v = vv[j];
                _Float16 h = (_Float16)v;
                a0[j] = h;
                a1[j] = (_Float16)((v - (float)h) * RS);
            }
            #pragma unroll
            for (int nf = 0; nf < 2; nf++) {
                aH[f][nf] = __builtin_amdgcn_mfma_f32_16x16x32_f16(a0, B0[nf], aH[f][nf], 0, 0, 0);
                aM[f][nf] = __builtin_amdgcn_mfma_f32_16x16x32_f16(a0, B1[nf], aM[f][nf], 0, 0, 0);
                aM[f][nf] = __builtin_amdgcn_mfma_f32_16x16x32_f16(a1, B0[nf], aM[f][nf], 0, 0, 0);
            }
        }
        __syncthreads();
    }
#undef STAGE

    // ---- write partials: part[slc][token][expert] ----
    // C/D layout (m89): col = lane&15 (expert), row = (lane>>4)*4 + r (token)
    const float i1 = 1.0f / RS;
    float* po = part + (size_t)slc * T_TOK * NEXP + (size_t)m0 * NEXP;
    #pragma unroll
    for (int f = 0; f < 2; f++)
        #pragma unroll
        for (int nf = 0; nf < 2; nf++)
            #pragma unroll
            for (int r = 0; r < 4; r++)
                po[(size_t)(wm * 32 + f * 16 + ag * 4 + r) * NEXP
                   + (wn * 2 + nf) * 16 + am]
                    = aH[f][nf][r] + aM[f][nf][r] * i1;
}

// ---- K2: reduce partials, sigmoid, +bias, top-8, normalize ----
// Token swizzle keeps reader XCD == writer XCD for partial locality.
__global__ __launch_bounds__(256) void reduce_topk(
    const float* __restrict__ part, const float* __restrict__ bias,
    float* __restrict__ out, int S)
{
    const int wave = threadIdx.x >> 6;
    const int lane = threadIdx.x & 63;
    const int j    = blockIdx.x;                 // 0..2047
    const int g    = j & 7;
    const int q    = j >> 3;
    const int token = g * 128 + (q & 31) * 4 + (q >> 5) * 1024 + wave;
    if (token >= T_TOK) return;

    float logit = 0.f;
    for (int s = 0; s < S; s++)
        logit += part[(size_t)s * T_TOK * NEXP + (size_t)token * NEXP + lane];

    float score  = 1.f / (1.f + expf(-logit));
    float biased = score + bias[lane];

    float my_sc = 0.f;
    int   my_idx = 0;
    float ssum  = 0.f;

    #pragma unroll
    for (int jj = 0; jj < TOPK; jj++) {
        float v = biased;
        int   i = lane;
        #pragma unroll
        for (int off = 32; off >= 1; off >>= 1) {
            float ov = __shfl_xor(v, off);
            int   oi = __shfl_xor(i, off);
            if (ov > v || (ov == v && oi < i)) { v = ov; i = oi; }
        }
        float s_sel = __shfl(score, i);
        ssum += s_sel;
        if (lane == jj) { my_idx = i; my_sc = s_sel; }
        if (lane == i) biased = -INFINITY;
    }

    if (lane < TOPK) {
        out[(size_t)token * TOPK + lane] = (float)my_idx;                 // indices as f32
        out[(size_t)T_TOK * TOPK + (size_t)token * TOPK + lane]
            = my_sc / (ssum + 1e-20f);                                    // weights
    }
}

extern "C" void kernel_launch(void* const* d_in, const int* in_sizes, int n_in,
                              void* d_out, int out_size, void* d_ws, size_t ws_size,
                              hipStream_t stream) {
    (void)in_sizes; (void)n_in; (void)out_size;
    const float* x    = (const float*)d_in[0];
    const float* gw   = (const float*)d_in[1];
    const float* bias = (const float*)d_in[2];
    float* out  = (float*)d_out;
    float* part = (float*)d_ws;                  // S x [T][E] f32

    const size_t per_slice = (size_t)T_TOK * NEXP * sizeof(float);       // 2 MiB
    int S = 1;
    for (int cand : {8, 4, 2}) {
        if ((size_t)cand * per_slice <= ws_size) { S = cand; break; }
    }

    dim3 b1(512);
    switch (S) {
        case 8: gemm_part<16, 8><<<dim3(64 * 8), b1, 0, stream>>>(x, gw, part); break;
        case 4: gemm_part<32, 4><<<dim3(64 * 4), b1, 0, stream>>>(x, gw, part); break;
        case 2: gemm_part<64, 2><<<dim3(64 * 2), b1, 0, stream>>>(x, gw, part); break;
        default: gemm_part<128, 1><<<dim3(64), b1, 0, stream>>>(x, gw, part); break;
    }

    reduce_topk<<<dim3(T_TOK / 4), 256, 0, stream>>>(part, bias, out, S);
}